// Round 2
// baseline (249.738 us; speedup 1.0000x reference)
//
#include <hip/hip_runtime.h>

#define B_ 512
#define L_ 8192
#define N_ 128
#define S_ 256
#define DELIM_ 5

// ---------------------------------------------------------------------------
// Kernel 1: per-row delimiter scan -> chunk starts / copy lengths.
// One block per row, 256 threads; each thread scans a contiguous 32-token
// slice so delimiter positions are emitted in order after a block exclusive
// scan of per-thread counts. Only the first N-1=127 delimiter positions
// matter (tail merge puts everything after delim #126 into chunk 127).
// ---------------------------------------------------------------------------
__global__ __launch_bounds__(256) void prep_kernel(const int* __restrict__ x,
                                                   int* __restrict__ chunk_start,
                                                   int* __restrict__ chunk_cl,
                                                   float* __restrict__ len_doc) {
    const int b = blockIdx.x;
    const int t = threadIdx.x;
    const int* row = x + (size_t)b * L_;
    const int per = L_ / 256;  // 32 tokens per thread
    const int base = t * per;

    int c = 0;
#pragma unroll
    for (int i = 0; i < per; ++i) c += (row[base + i] == DELIM_);

    // wave-level inclusive scan (wave = 64)
    const int lane = t & 63;
    const int wid = t >> 6;
    int v = c;
#pragma unroll
    for (int d = 1; d < 64; d <<= 1) {
        int n = __shfl_up(v, d, 64);
        if (lane >= d) v += n;
    }

    __shared__ int s_wsum[4];
    __shared__ int s_dpos[N_ - 1];  // first 127 delimiter positions
    if (lane == 63) s_wsum[wid] = v;
    __syncthreads();

    int woff = 0;
    for (int w = 0; w < wid; ++w) woff += s_wsum[w];
    const int m = s_wsum[0] + s_wsum[1] + s_wsum[2] + s_wsum[3];  // total delims in row
    const int off = woff + v - c;  // exclusive prefix for this thread

    if (c > 0 && off < N_ - 1) {
        int o = off;
        for (int i = 0; i < per; ++i) {
            if (row[base + i] == DELIM_) {
                if (o < N_ - 1) s_dpos[o] = base + i;
                ++o;
            }
        }
    }
    __syncthreads();

    if (t < N_) {
        const int k = t;
        const int mc = (m < N_ - 1) ? m : (N_ - 1);  // index of last used chunk
        int start = 0, cl = 0;
        if (k <= mc) {
            start = (k == 0) ? 0 : (s_dpos[k - 1] + 1);
            const int end = (k < mc) ? s_dpos[k] : L_;  // rpad position L = trailing DELIM
            const int size = end - start + 1;
            cl = (size <= 1) ? 0 : (size < S_ ? size : S_);
        }
        chunk_start[b * N_ + k] = start;
        chunk_cl[b * N_ + k] = cl;
    }
    if (t == 0) len_doc[b] = 0.0f;  // zero before fill_kernel's atomics
}

// ---------------------------------------------------------------------------
// Kernel 2: one block per (b,k) sentence. Gather tokens (coalesced, contiguous
// per chunk), write otp, count nonzero tokens (len_sent), write mask, bump
// len_doc. All outputs written as FLOAT — the harness reads the flat tuple
// buffer as float32 (int32 stores reinterpret as denormals ~= 0: R1 failure).
// ---------------------------------------------------------------------------
__global__ __launch_bounds__(256) void fill_kernel(const int* __restrict__ x,
                                                   const int* __restrict__ chunk_start,
                                                   const int* __restrict__ chunk_cl,
                                                   float* __restrict__ otp,
                                                   float* __restrict__ mask,
                                                   float* __restrict__ len_doc) {
    const int k = blockIdx.x;
    const int b = blockIdx.y;
    const int idx = b * N_ + k;
    const int s = threadIdx.x;

    const int start = chunk_start[idx];
    const int cl = chunk_cl[idx];

    int tok = 0;
    if (s < cl) {
        const int j = start + s;
        tok = (j < L_) ? x[(size_t)b * L_ + j] : DELIM_;  // rpad[L] = DELIM
    }
    otp[(size_t)idx * S_ + s] = (float)tok;

    const unsigned long long ball = __ballot(tok != 0);
    __shared__ int s_cnt[4];
    const int lane = s & 63;
    const int wid = s >> 6;
    if (lane == 0) s_cnt[wid] = __popcll(ball);
    __syncthreads();
    const int len = s_cnt[0] + s_cnt[1] + s_cnt[2] + s_cnt[3];

    mask[(size_t)idx * S_ + s] = (s < len) ? 1.0f : 0.0f;
    if (s == 0 && len != 0) atomicAdd(&len_doc[b], 1.0f);
}

extern "C" void kernel_launch(void* const* d_in, const int* in_sizes, int n_in,
                              void* d_out, int out_size, void* d_ws, size_t ws_size,
                              hipStream_t stream) {
    const int* x = (const int*)d_in[0];
    float* out = (float*)d_out;

    // d_out layout (flat, return order): otp[B*N*S] | len_doc[B] | mask[B*N*S]
    float* otp = out;
    float* len_doc = out + (size_t)B_ * N_ * S_;
    float* mask = len_doc + B_;

    int* chunk_start = (int*)d_ws;            // B*N ints
    int* chunk_cl = chunk_start + B_ * N_;    // B*N ints

    prep_kernel<<<B_, 256, 0, stream>>>(x, chunk_start, chunk_cl, len_doc);
    fill_kernel<<<dim3(N_, B_), 256, 0, stream>>>(x, chunk_start, chunk_cl, otp, mask, len_doc);
}

// Round 3
// 143.345 us; speedup vs baseline: 1.7422x; 1.7422x over previous
//
#include <hip/hip_runtime.h>

#define B_ 512
#define L_ 8192
#define N_ 128
#define S_ 256
#define DELIM_ 5
#define T_ 512           // threads per block (8 waves)
#define NW_ (T_ / 64)    // 8 waves per block
#define PER_ (L_ / T_)   // 16 tokens per thread in scan phase

// One block per row. Phase 1: delimiter scan -> chunk table in LDS.
// Phase 2: one sentence per wave per iteration (64 lanes x 4 elems = S=256),
// float4 stores, in-wave butterfly for len_sent, no barriers/atomics in loop.
__global__ __launch_bounds__(T_) void split_kernel(const int* __restrict__ x,
                                                   float* __restrict__ otp,
                                                   float* __restrict__ len_doc,
                                                   float* __restrict__ mask) {
    const int b = blockIdx.x;
    const int t = threadIdx.x;
    const int lane = t & 63;
    const int w = t >> 6;
    const int* __restrict__ row = x + (size_t)b * L_;

    __shared__ int s_wsum[NW_];
    __shared__ int s_dpos[N_ - 1];  // first 127 delimiter positions (tail merge)
    __shared__ int s_start[N_];
    __shared__ int s_cl[N_];        // copy length: 0 for empty/unused, else min(size, S)
    __shared__ int s_doc[NW_];

    // ---- phase 1a: count delimiters in this thread's contiguous slice ----
    const int base = t * PER_;
    int c = 0;
#pragma unroll
    for (int i = 0; i < PER_; ++i) c += (row[base + i] == DELIM_);

    // wave inclusive scan
    int v = c;
#pragma unroll
    for (int d = 1; d < 64; d <<= 1) {
        int n = __shfl_up(v, d, 64);
        if (lane >= d) v += n;
    }
    if (lane == 63) s_wsum[w] = v;
    __syncthreads();

    int woff = 0, m = 0;
#pragma unroll
    for (int i = 0; i < NW_; ++i) {
        const int sv = s_wsum[i];
        if (i < w) woff += sv;
        m += sv;  // total delimiters in row
    }
    const int off = woff + v - c;  // exclusive prefix for this thread

    // ---- phase 1b: emit ordered delimiter positions (only first N-1 matter) ----
    if (c > 0 && off < N_ - 1) {
        int o = off;
        for (int i = 0; i < PER_; ++i) {
            if (row[base + i] == DELIM_) {
                if (o < N_ - 1) s_dpos[o] = base + i;
                ++o;
            }
        }
    }
    __syncthreads();

    // ---- phase 1c: chunk table ----
    if (t < N_) {
        const int k = t;
        const int mc = (m < N_ - 1) ? m : (N_ - 1);  // last used chunk index
        int start = 0, cl = 0;
        if (k <= mc) {
            start = (k == 0) ? 0 : (s_dpos[k - 1] + 1);
            const int end = (k < mc) ? s_dpos[k] : L_;  // rpad[L] = trailing DELIM
            const int size = end - start + 1;           // delimiter belongs to its chunk
            cl = (size <= 1) ? 0 : (size < S_ ? size : S_);  // lone delim -> all PAD
        }
        s_start[k] = start;
        s_cl[k] = cl;
    }
    __syncthreads();

    // ---- phase 2: write outputs; wave w handles sentence k = i*NW_ + w ----
    float* __restrict__ otp_b = otp + (size_t)b * N_ * S_;
    float* __restrict__ msk_b = mask + (size_t)b * N_ * S_;
    int doccnt = 0;
    for (int i = 0; i < (N_ / NW_); ++i) {
        const int k = i * NW_ + w;
        const int start = s_start[k];  // wave-uniform LDS broadcast
        const int cl = s_cl[k];
        const int s0 = lane * 4;
        float tf[4];
        int nz = 0;
#pragma unroll
        for (int j = 0; j < 4; ++j) {
            const int e = s0 + j;
            int tok = 0;
            if (e < cl) {
                const int g = start + e;
                tok = (g < L_) ? row[g] : DELIM_;  // L1/L2 hit: row read in phase 1
            }
            tf[j] = (float)tok;
            nz += (tok != 0);
        }
        // in-wave butterfly sum -> len_sent (uniform across wave)
        int len = nz;
#pragma unroll
        for (int d = 32; d >= 1; d >>= 1) len += __shfl_xor(len, d, 64);

        *(float4*)(otp_b + (size_t)k * S_ + s0) =
            make_float4(tf[0], tf[1], tf[2], tf[3]);
        *(float4*)(msk_b + (size_t)k * S_ + s0) =
            make_float4(s0 < len ? 1.0f : 0.0f, s0 + 1 < len ? 1.0f : 0.0f,
                        s0 + 2 < len ? 1.0f : 0.0f, s0 + 3 < len ? 1.0f : 0.0f);
        doccnt += (len > 0);
    }

    // ---- len_doc: one LDS reduction per block, no atomics ----
    if (lane == 0) s_doc[w] = doccnt;
    __syncthreads();
    if (t == 0) {
        int d = 0;
#pragma unroll
        for (int i = 0; i < NW_; ++i) d += s_doc[i];
        len_doc[b] = (float)d;
    }
}

extern "C" void kernel_launch(void* const* d_in, const int* in_sizes, int n_in,
                              void* d_out, int out_size, void* d_ws, size_t ws_size,
                              hipStream_t stream) {
    const int* x = (const int*)d_in[0];
    float* out = (float*)d_out;

    // d_out layout (flat, return order): otp[B*N*S] | len_doc[B] | mask[B*N*S]
    float* otp = out;
    float* len_doc = out + (size_t)B_ * N_ * S_;
    float* mask = len_doc + B_;

    split_kernel<<<B_, T_, 0, stream>>>(x, otp, len_doc, mask);
}